// Round 8
// baseline (328.604 us; speedup 1.0000x reference)
//
#include <hip/hip_runtime.h>
#include <stdint.h>

#define DIN 96
#define DP 48
#define NPOS (48*48*48)   // 110592
#define NG 1728           // 12^3
#define WIN3 343
#define NCH 64
#define NC2 32

// ---------------------------------------------------------------------------
// MEASUREMENT ROUND: dwconv8 launched 5x (idempotent). All kernels otherwise
// byte-identical to round 7. A = (T_new - T_r7) / 4.
// ---------------------------------------------------------------------------

// ---------------------------------------------------------------------------
// Kernel A: depthwise 3x3x3 stride-2 pad-1 conv + bias -> dwout[c][pos]
// ---------------------------------------------------------------------------
__global__ __launch_bounds__(256) void dwconv8(
    const float* __restrict__ feat,   // [64][96][96][96]
    const float* __restrict__ dw_w,   // [64][27]
    const float* __restrict__ dw_b,   // [64]
    float* __restrict__ dwout)        // [64][NPOS]
{
    const int c   = blockIdx.y;
    const int idx = blockIdx.x * 256 + threadIdx.x;   // 0..13823
    const int t   = idx % 12;                         // w-quad (out w = 4t..4t+3)
    const int oh  = (idx / 12) % 48;
    const int odp = idx / (12 * 48);                  // d-pair (out d = 2odp,2odp+1)

    const float* fc = feat + (size_t)c * (DIN * DIN * DIN);
    const float* wc = dw_w + c * 27;
    float w[27];
    #pragma unroll
    for (int i = 0; i < 27; ++i) w[i] = wc[i];        // wave-uniform

    float acc[2][4];
    #pragma unroll
    for (int i = 0; i < 2; ++i)
        #pragma unroll
        for (int j = 0; j < 4; ++j) acc[i][j] = 0.0f;

    #pragma unroll
    for (int dd = 0; dd < 5; ++dd) {
        const int id = 4 * odp - 1 + dd;              // input plane
        if (id >= 0) {
            #pragma unroll
            for (int kh = 0; kh < 3; ++kh) {
                const int ih = 2 * oh - 1 + kh;       // input row
                if (ih >= 0) {
                    const float* row = fc + ((size_t)id * DIN + ih) * DIN + 8 * t;
                    const float4 a4 = *(const float4*)(row);
                    const float4 b4 = *(const float4*)(row + 4);
                    const float  s  = (t > 0) ? row[-1] : 0.0f;   // w = 8t-1 (pad 0)
                    #pragma unroll
                    for (int half = 0; half < 2; ++half) {
                        if ((half == 0 && dd <= 2) || (half == 1 && dd >= 2)) {
                            const int kd = (half == 0) ? dd : dd - 2;
                            const float w0 = w[(kd * 3 + kh) * 3 + 0];
                            const float w1 = w[(kd * 3 + kh) * 3 + 1];
                            const float w2 = w[(kd * 3 + kh) * 3 + 2];
                            acc[half][0] = fmaf(s,    w0, fmaf(a4.x, w1, fmaf(a4.y, w2, acc[half][0])));
                            acc[half][1] = fmaf(a4.y, w0, fmaf(a4.z, w1, fmaf(a4.w, w2, acc[half][1])));
                            acc[half][2] = fmaf(a4.w, w0, fmaf(b4.x, w1, fmaf(b4.y, w2, acc[half][2])));
                            acc[half][3] = fmaf(b4.y, w0, fmaf(b4.z, w1, fmaf(b4.w, w2, acc[half][3])));
                        }
                    }
                }
            }
        }
    }

    const float b = dw_b[c];
    const size_t base = (size_t)c * NPOS + (((size_t)(2 * odp) * DP + oh) * DP) + 4 * t;
    *(float4*)(dwout + base)           = make_float4(acc[0][0] + b, acc[0][1] + b, acc[0][2] + b, acc[0][3] + b);
    *(float4*)(dwout + base + DP * DP) = make_float4(acc[1][0] + b, acc[1][1] + b, acc[1][2] + b, acc[1][3] + b);
}

// ---------------------------------------------------------------------------
// Kernel B1: pointwise (64->32)+bias+ReLU -> f2T[32][NPOS] (transposed)
// ---------------------------------------------------------------------------
__global__ __launch_bounds__(256) void pw1(
    const float* __restrict__ dwout,  // [64][NPOS]
    const float* __restrict__ pw_w,   // [32][64]
    const float* __restrict__ pw_b,   // [32]
    float* __restrict__ f2T)          // [32][NPOS]
{
    __shared__ float swT[NCH * NC2];  // swT[c*32+o] = pw_w[o*64+c]
    __shared__ float sb[NC2];
    const int tid = threadIdx.x;

    for (int i = tid; i < NCH * NC2; i += 256) {
        const int o = i & 31, c = i >> 5;
        swT[i] = pw_w[o * NCH + c];
    }
    if (tid < NC2) sb[tid] = pw_b[tid];
    __syncthreads();

    const int g  = blockIdx.x * 256 + tid;
    const int oq = g & 7;             // out-ch group: 4*oq .. 4*oq+3
    const int p4 = g >> 3;            // positions 4*p4 .. 4*p4+3

    float acc[4][4];                  // [ch][pos]
    #pragma unroll
    for (int i = 0; i < 4; ++i) {
        const float b = sb[oq * 4 + i];
        #pragma unroll
        for (int j = 0; j < 4; ++j) acc[i][j] = b;
    }

    const float* xp = dwout + 4 * (size_t)p4;
    #pragma unroll 4
    for (int c = 0; c < NCH; ++c) {
        const float4 x4 = *(const float4*)(xp + (size_t)c * NPOS);
        const float4 w4 = *(const float4*)(swT + c * NC2 + oq * 4);
        const float xs[4] = {x4.x, x4.y, x4.z, x4.w};
        const float ws[4] = {w4.x, w4.y, w4.z, w4.w};
        #pragma unroll
        for (int i = 0; i < 4; ++i)
            #pragma unroll
            for (int j = 0; j < 4; ++j)
                acc[i][j] = fmaf(ws[i], xs[j], acc[i][j]);
    }

    #pragma unroll
    for (int i = 0; i < 4; ++i) {
        const int o = oq * 4 + i;
        *(float4*)(f2T + (size_t)o * NPOS + 4 * p4) =
            make_float4(fmaxf(acc[i][0], 0.f), fmaxf(acc[i][1], 0.f),
                        fmaxf(acc[i][2], 0.f), fmaxf(acc[i][3], 0.f));
    }
}

// ---------------------------------------------------------------------------
// Kernel B2: V projection (32->64) -> V[pos][64]
// ---------------------------------------------------------------------------
__global__ __launch_bounds__(256) void pw2(
    const float* __restrict__ f2T,    // [32][NPOS]
    const float* __restrict__ v_w,    // [64][32]
    float* __restrict__ V)            // [NPOS][64]
{
    __shared__ float svT[NC2 * NCH];  // svT[o*64+j] = v_w[j*32+o]
    const int tid = threadIdx.x;

    for (int i = tid; i < NC2 * NCH; i += 256) {
        const int j = i & 63, o = i >> 6;
        svT[i] = v_w[j * NC2 + o];
    }
    __syncthreads();

    const int g  = blockIdx.x * 256 + tid;
    const int jq = g & 7;             // V-row group: 8*jq .. 8*jq+7
    const int p2 = g >> 3;            // positions 2*p2, 2*p2+1

    float acc[8][2];
    #pragma unroll
    for (int i = 0; i < 8; ++i) { acc[i][0] = 0.f; acc[i][1] = 0.f; }

    const float* xp = f2T + 2 * (size_t)p2;
    #pragma unroll 4
    for (int o = 0; o < NC2; ++o) {
        const float2 x2 = *(const float2*)(xp + (size_t)o * NPOS);
        const float4 wA = *(const float4*)(svT + o * NCH + jq * 8);
        const float4 wB = *(const float4*)(svT + o * NCH + jq * 8 + 4);
        const float ws[8] = {wA.x, wA.y, wA.z, wA.w, wB.x, wB.y, wB.z, wB.w};
        #pragma unroll
        for (int i = 0; i < 8; ++i) {
            acc[i][0] = fmaf(ws[i], x2.x, acc[i][0]);
            acc[i][1] = fmaf(ws[i], x2.y, acc[i][1]);
        }
    }

    #pragma unroll
    for (int pp = 0; pp < 2; ++pp) {
        float* vp = V + (size_t)(2 * p2 + pp) * NCH + jq * 8;
        *(float4*)(vp)     = make_float4(acc[0][pp], acc[1][pp], acc[2][pp], acc[3][pp]);
        *(float4*)(vp + 4) = make_float4(acc[4][pp], acc[5][pp], acc[6][pp], acc[7][pp]);
    }
}

// ---------------------------------------------------------------------------
// Kernel B3: K scores (prescaled rows 0,32 of k_w) -> Ksc[2][NPOS]
// ---------------------------------------------------------------------------
__global__ __launch_bounds__(256) void ksc_k(
    const float* __restrict__ f2T,    // [32][NPOS]
    const float* __restrict__ k_w,    // [64][32]
    float* __restrict__ Ksc)          // [2][NPOS]
{
    __shared__ float sk[NC2 * 2];     // sk[o*2+h]
    const int tid = threadIdx.x;
    if (tid < 64) {
        const int o = tid >> 1, h = tid & 1;
        sk[tid] = k_w[(h * 32) * NC2 + o] * 0.17677669529663687f;
    }
    __syncthreads();

    const int pos = blockIdx.x * 256 + tid;
    float k0 = 0.f, k1 = 0.f;
    #pragma unroll 8
    for (int o = 0; o < NC2; ++o) {
        const float x = f2T[(size_t)o * NPOS + pos];
        k0 = fmaf(sk[o * 2 + 0], x, k0);
        k1 = fmaf(sk[o * 2 + 1], x, k1);
    }
    Ksc[pos] = k0;
    Ksc[NPOS + pos] = k1;
}

// ---------------------------------------------------------------------------
// Kernel C: per-center windowed attention + output head (heads in parallel).
// ---------------------------------------------------------------------------
__global__ __launch_bounds__(256) void attn_out(
    const float* __restrict__ V,      // [NPOS][64]
    const float* __restrict__ Ksc,    // [2][NPOS]
    const float* __restrict__ out_w,  // [3][64]
    const float* __restrict__ out_b,  // [3]
    float* __restrict__ out)          // [3][NG]
{
    const int lo_t[12] = {0,1,5,9,14,18,22,26,31,35,39,44};
    const int hi_t[12] = {4,8,12,16,21,25,29,33,38,42,46,48};

    const int g    = blockIdx.x;
    const int tid  = threadIdx.x;
    const int lane = tid & 63;
    const int wv   = tid >> 6;
    const int h    = wv >> 1;         // score-phase head
    const int p    = tid & 127;       // index within head pair, 0..127

    const int gz = g % 12, gy = (g / 12) % 12, gx = g / 144;
    const int lox = lo_t[gx], hix = hi_t[gx];
    const int loy = lo_t[gy], hiy = hi_t[gy];
    const int loz = lo_t[gz], hiz = hi_t[gz];

    __shared__ int   s_flat[WIN3];        // bit31 set => masked out
    __shared__ float s_attn[2][WIN3];
    __shared__ float s_red[4];
    __shared__ float s_red2[4];
    __shared__ float s_gsum[2];
    __shared__ float s_pctx[4][NCH];
    __shared__ float s_ctx[NCH];

    for (int w = tid; w < WIN3; w += 256) {
        int kd = w / 49, kh = (w / 7) % 7, kw = w % 7;
        int ix = lox + kd, iy = loy + kh, iz = loz + kw;
        bool m = (ix < hix) && (iy < hiy) && (iz < hiz);
        if (ix >= hix) ix = lox;
        if (iy >= hiy) iy = loy;
        if (iz >= hiz) iz = loz;
        int flat = (ix * DP + iy) * DP + iz;
        s_flat[w] = m ? flat : (flat | (int)0x80000000);
    }
    __syncthreads();

    const float NEG_INF = -__builtin_inff();

    float sc0 = NEG_INF, sc1 = NEG_INF, sc2 = NEG_INF;
    {
        int fv = s_flat[p];
        if (fv >= 0) sc0 = Ksc[h * NPOS + fv];
        fv = s_flat[p + 128];
        if (fv >= 0) sc1 = Ksc[h * NPOS + fv];
        if (p + 256 < WIN3) {
            fv = s_flat[p + 256];
            if (fv >= 0) sc2 = Ksc[h * NPOS + fv];
        }
    }

    float lmax = fmaxf(fmaxf(sc0, sc1), sc2);
    #pragma unroll
    for (int off = 32; off; off >>= 1) lmax = fmaxf(lmax, __shfl_xor(lmax, off));
    if (lane == 0) s_red[wv] = lmax;
    __syncthreads();
    const float gmax = fmaxf(s_red[2 * h], s_red[2 * h + 1]);

    float e0 = (sc0 == NEG_INF) ? 0.0f : expf(sc0 - gmax);
    float e1 = (sc1 == NEG_INF) ? 0.0f : expf(sc1 - gmax);
    float e2 = 0.0f;
    s_attn[h][p]       = e0;
    s_attn[h][p + 128] = e1;
    if (p + 256 < WIN3) {
        e2 = (sc2 == NEG_INF) ? 0.0f : expf(sc2 - gmax);
        s_attn[h][p + 256] = e2;
    }
    float lsum = e0 + e1 + e2;
    #pragma unroll
    for (int off = 32; off; off >>= 1) lsum += __shfl_xor(lsum, off);
    if (lane == 0) s_red2[wv] = lsum;
    __syncthreads();
    if (tid < 2) s_gsum[tid] = s_red2[2 * tid] + s_red2[2 * tid + 1];
    __syncthreads();

    const int hh = lane >> 5;
    float acc = 0.0f;
    for (int w = wv; w < WIN3; w += 4) {
        int fv = s_flat[w] & 0x7fffffff;
        acc = fmaf(s_attn[hh][w], V[(size_t)fv * NCH + lane], acc);
    }

    s_pctx[wv][lane] = acc;
    __syncthreads();
    if (wv == 0) {
        float ctx = s_pctx[0][lane] + s_pctx[1][lane] + s_pctx[2][lane] + s_pctx[3][lane];
        s_ctx[lane] = ctx / s_gsum[hh];
    }
    __syncthreads();

    if (tid < 3) {
        float a = out_b[tid];
        #pragma unroll
        for (int j = 0; j < NCH; ++j) a = fmaf(out_w[tid * NCH + j], s_ctx[j], a);
        out[tid * NG + g] = a;
    }
}

// ---------------------------------------------------------------------------
extern "C" void kernel_launch(void* const* d_in, const int* in_sizes, int n_in,
                              void* d_out, int out_size, void* d_ws, size_t ws_size,
                              hipStream_t stream) {
    const float* feat  = (const float*)d_in[0];
    const float* dw_w  = (const float*)d_in[1];
    const float* dw_b  = (const float*)d_in[2];
    const float* pw_w  = (const float*)d_in[3];
    const float* pw_b  = (const float*)d_in[4];
    const float* k_w   = (const float*)d_in[5];
    const float* v_w   = (const float*)d_in[6];
    const float* out_w = (const float*)d_in[7];
    const float* out_b = (const float*)d_in[8];
    float* out = (float*)d_out;

    float* dwout = (float*)d_ws;                        // [64][NPOS]   28 MB
    float* f2T   = dwout + (size_t)NCH * NPOS;          // [32][NPOS]   14 MB
    float* V     = f2T + (size_t)NC2 * NPOS;            // [NPOS][64]   28 MB
    float* Ksc   = V + (size_t)NPOS * NCH;              // [2][NPOS]    .9 MB

    // PROBE: 5x identical idempotent launches of dwconv8.
    // A_clean = (T_this_round - T_round7) / 4.
    for (int rep = 0; rep < 5; ++rep) {
        hipLaunchKernelGGL(dwconv8, dim3(54, NCH), dim3(256), 0, stream,
                           feat, dw_w, dw_b, dwout);
    }
    hipLaunchKernelGGL(pw1, dim3(NPOS * 2 / 256), dim3(256), 0, stream,   // 864 blocks
                       dwout, pw_w, pw_b, f2T);
    hipLaunchKernelGGL(pw2, dim3(NPOS * 4 / 256), dim3(256), 0, stream,   // 1728 blocks
                       f2T, v_w, V);
    hipLaunchKernelGGL(ksc_k, dim3(NPOS / 256), dim3(256), 0, stream,     // 432 blocks
                       f2T, k_w, Ksc);
    hipLaunchKernelGGL(attn_out, dim3(NG), dim3(256), 0, stream,
                       V, Ksc, out_w, out_b, out);
}

// Round 9
// 274.078 us; speedup vs baseline: 1.1989x; 1.1989x over previous
//
#include <hip/hip_runtime.h>
#include <stdint.h>

#define DIN 96
#define DP 48
#define NPOS (48*48*48)   // 110592
#define NG 1728           // 12^3
#define WIN3 343
#define NCH 64
#define NC2 32

// ---------------------------------------------------------------------------
// MEASUREMENT ROUND 2: attn_out launched 5x (idempotent). All kernels
// byte-identical to round 7. A_attn = (T_new - 133.7) / 4.
// Known so far: dwconv8 = 48.7 us, back half total = 85 us.
// ---------------------------------------------------------------------------

// ---------------------------------------------------------------------------
// Kernel A: depthwise 3x3x3 stride-2 pad-1 conv + bias -> dwout[c][pos]
// ---------------------------------------------------------------------------
__global__ __launch_bounds__(256) void dwconv8(
    const float* __restrict__ feat,   // [64][96][96][96]
    const float* __restrict__ dw_w,   // [64][27]
    const float* __restrict__ dw_b,   // [64]
    float* __restrict__ dwout)        // [64][NPOS]
{
    const int c   = blockIdx.y;
    const int idx = blockIdx.x * 256 + threadIdx.x;   // 0..13823
    const int t   = idx % 12;                         // w-quad (out w = 4t..4t+3)
    const int oh  = (idx / 12) % 48;
    const int odp = idx / (12 * 48);                  // d-pair (out d = 2odp,2odp+1)

    const float* fc = feat + (size_t)c * (DIN * DIN * DIN);
    const float* wc = dw_w + c * 27;
    float w[27];
    #pragma unroll
    for (int i = 0; i < 27; ++i) w[i] = wc[i];        // wave-uniform

    float acc[2][4];
    #pragma unroll
    for (int i = 0; i < 2; ++i)
        #pragma unroll
        for (int j = 0; j < 4; ++j) acc[i][j] = 0.0f;

    #pragma unroll
    for (int dd = 0; dd < 5; ++dd) {
        const int id = 4 * odp - 1 + dd;              // input plane
        if (id >= 0) {
            #pragma unroll
            for (int kh = 0; kh < 3; ++kh) {
                const int ih = 2 * oh - 1 + kh;       // input row
                if (ih >= 0) {
                    const float* row = fc + ((size_t)id * DIN + ih) * DIN + 8 * t;
                    const float4 a4 = *(const float4*)(row);
                    const float4 b4 = *(const float4*)(row + 4);
                    const float  s  = (t > 0) ? row[-1] : 0.0f;   // w = 8t-1 (pad 0)
                    #pragma unroll
                    for (int half = 0; half < 2; ++half) {
                        if ((half == 0 && dd <= 2) || (half == 1 && dd >= 2)) {
                            const int kd = (half == 0) ? dd : dd - 2;
                            const float w0 = w[(kd * 3 + kh) * 3 + 0];
                            const float w1 = w[(kd * 3 + kh) * 3 + 1];
                            const float w2 = w[(kd * 3 + kh) * 3 + 2];
                            acc[half][0] = fmaf(s,    w0, fmaf(a4.x, w1, fmaf(a4.y, w2, acc[half][0])));
                            acc[half][1] = fmaf(a4.y, w0, fmaf(a4.z, w1, fmaf(a4.w, w2, acc[half][1])));
                            acc[half][2] = fmaf(a4.w, w0, fmaf(b4.x, w1, fmaf(b4.y, w2, acc[half][2])));
                            acc[half][3] = fmaf(b4.y, w0, fmaf(b4.z, w1, fmaf(b4.w, w2, acc[half][3])));
                        }
                    }
                }
            }
        }
    }

    const float b = dw_b[c];
    const size_t base = (size_t)c * NPOS + (((size_t)(2 * odp) * DP + oh) * DP) + 4 * t;
    *(float4*)(dwout + base)           = make_float4(acc[0][0] + b, acc[0][1] + b, acc[0][2] + b, acc[0][3] + b);
    *(float4*)(dwout + base + DP * DP) = make_float4(acc[1][0] + b, acc[1][1] + b, acc[1][2] + b, acc[1][3] + b);
}

// ---------------------------------------------------------------------------
// Kernel B1: pointwise (64->32)+bias+ReLU -> f2T[32][NPOS] (transposed)
// ---------------------------------------------------------------------------
__global__ __launch_bounds__(256) void pw1(
    const float* __restrict__ dwout,  // [64][NPOS]
    const float* __restrict__ pw_w,   // [32][64]
    const float* __restrict__ pw_b,   // [32]
    float* __restrict__ f2T)          // [32][NPOS]
{
    __shared__ float swT[NCH * NC2];  // swT[c*32+o] = pw_w[o*64+c]
    __shared__ float sb[NC2];
    const int tid = threadIdx.x;

    for (int i = tid; i < NCH * NC2; i += 256) {
        const int o = i & 31, c = i >> 5;
        swT[i] = pw_w[o * NCH + c];
    }
    if (tid < NC2) sb[tid] = pw_b[tid];
    __syncthreads();

    const int g  = blockIdx.x * 256 + tid;
    const int oq = g & 7;             // out-ch group: 4*oq .. 4*oq+3
    const int p4 = g >> 3;            // positions 4*p4 .. 4*p4+3

    float acc[4][4];                  // [ch][pos]
    #pragma unroll
    for (int i = 0; i < 4; ++i) {
        const float b = sb[oq * 4 + i];
        #pragma unroll
        for (int j = 0; j < 4; ++j) acc[i][j] = b;
    }

    const float* xp = dwout + 4 * (size_t)p4;
    #pragma unroll 4
    for (int c = 0; c < NCH; ++c) {
        const float4 x4 = *(const float4*)(xp + (size_t)c * NPOS);
        const float4 w4 = *(const float4*)(swT + c * NC2 + oq * 4);
        const float xs[4] = {x4.x, x4.y, x4.z, x4.w};
        const float ws[4] = {w4.x, w4.y, w4.z, w4.w};
        #pragma unroll
        for (int i = 0; i < 4; ++i)
            #pragma unroll
            for (int j = 0; j < 4; ++j)
                acc[i][j] = fmaf(ws[i], xs[j], acc[i][j]);
    }

    #pragma unroll
    for (int i = 0; i < 4; ++i) {
        const int o = oq * 4 + i;
        *(float4*)(f2T + (size_t)o * NPOS + 4 * p4) =
            make_float4(fmaxf(acc[i][0], 0.f), fmaxf(acc[i][1], 0.f),
                        fmaxf(acc[i][2], 0.f), fmaxf(acc[i][3], 0.f));
    }
}

// ---------------------------------------------------------------------------
// Kernel B2: V projection (32->64) -> V[pos][64]
// ---------------------------------------------------------------------------
__global__ __launch_bounds__(256) void pw2(
    const float* __restrict__ f2T,    // [32][NPOS]
    const float* __restrict__ v_w,    // [64][32]
    float* __restrict__ V)            // [NPOS][64]
{
    __shared__ float svT[NC2 * NCH];  // svT[o*64+j] = v_w[j*32+o]
    const int tid = threadIdx.x;

    for (int i = tid; i < NC2 * NCH; i += 256) {
        const int j = i & 63, o = i >> 6;
        svT[i] = v_w[j * NC2 + o];
    }
    __syncthreads();

    const int g  = blockIdx.x * 256 + tid;
    const int jq = g & 7;             // V-row group: 8*jq .. 8*jq+7
    const int p2 = g >> 3;            // positions 2*p2, 2*p2+1

    float acc[8][2];
    #pragma unroll
    for (int i = 0; i < 8; ++i) { acc[i][0] = 0.f; acc[i][1] = 0.f; }

    const float* xp = f2T + 2 * (size_t)p2;
    #pragma unroll 4
    for (int o = 0; o < NC2; ++o) {
        const float2 x2 = *(const float2*)(xp + (size_t)o * NPOS);
        const float4 wA = *(const float4*)(svT + o * NCH + jq * 8);
        const float4 wB = *(const float4*)(svT + o * NCH + jq * 8 + 4);
        const float ws[8] = {wA.x, wA.y, wA.z, wA.w, wB.x, wB.y, wB.z, wB.w};
        #pragma unroll
        for (int i = 0; i < 8; ++i) {
            acc[i][0] = fmaf(ws[i], x2.x, acc[i][0]);
            acc[i][1] = fmaf(ws[i], x2.y, acc[i][1]);
        }
    }

    #pragma unroll
    for (int pp = 0; pp < 2; ++pp) {
        float* vp = V + (size_t)(2 * p2 + pp) * NCH + jq * 8;
        *(float4*)(vp)     = make_float4(acc[0][pp], acc[1][pp], acc[2][pp], acc[3][pp]);
        *(float4*)(vp + 4) = make_float4(acc[4][pp], acc[5][pp], acc[6][pp], acc[7][pp]);
    }
}

// ---------------------------------------------------------------------------
// Kernel B3: K scores (prescaled rows 0,32 of k_w) -> Ksc[2][NPOS]
// ---------------------------------------------------------------------------
__global__ __launch_bounds__(256) void ksc_k(
    const float* __restrict__ f2T,    // [32][NPOS]
    const float* __restrict__ k_w,    // [64][32]
    float* __restrict__ Ksc)          // [2][NPOS]
{
    __shared__ float sk[NC2 * 2];     // sk[o*2+h]
    const int tid = threadIdx.x;
    if (tid < 64) {
        const int o = tid >> 1, h = tid & 1;
        sk[tid] = k_w[(h * 32) * NC2 + o] * 0.17677669529663687f;
    }
    __syncthreads();

    const int pos = blockIdx.x * 256 + tid;
    float k0 = 0.f, k1 = 0.f;
    #pragma unroll 8
    for (int o = 0; o < NC2; ++o) {
        const float x = f2T[(size_t)o * NPOS + pos];
        k0 = fmaf(sk[o * 2 + 0], x, k0);
        k1 = fmaf(sk[o * 2 + 1], x, k1);
    }
    Ksc[pos] = k0;
    Ksc[NPOS + pos] = k1;
}

// ---------------------------------------------------------------------------
// Kernel C: per-center windowed attention + output head (heads in parallel).
// ---------------------------------------------------------------------------
__global__ __launch_bounds__(256) void attn_out(
    const float* __restrict__ V,      // [NPOS][64]
    const float* __restrict__ Ksc,    // [2][NPOS]
    const float* __restrict__ out_w,  // [3][64]
    const float* __restrict__ out_b,  // [3]
    float* __restrict__ out)          // [3][NG]
{
    const int lo_t[12] = {0,1,5,9,14,18,22,26,31,35,39,44};
    const int hi_t[12] = {4,8,12,16,21,25,29,33,38,42,46,48};

    const int g    = blockIdx.x;
    const int tid  = threadIdx.x;
    const int lane = tid & 63;
    const int wv   = tid >> 6;
    const int h    = wv >> 1;         // score-phase head
    const int p    = tid & 127;       // index within head pair, 0..127

    const int gz = g % 12, gy = (g / 12) % 12, gx = g / 144;
    const int lox = lo_t[gx], hix = hi_t[gx];
    const int loy = lo_t[gy], hiy = hi_t[gy];
    const int loz = lo_t[gz], hiz = hi_t[gz];

    __shared__ int   s_flat[WIN3];        // bit31 set => masked out
    __shared__ float s_attn[2][WIN3];
    __shared__ float s_red[4];
    __shared__ float s_red2[4];
    __shared__ float s_gsum[2];
    __shared__ float s_pctx[4][NCH];
    __shared__ float s_ctx[NCH];

    for (int w = tid; w < WIN3; w += 256) {
        int kd = w / 49, kh = (w / 7) % 7, kw = w % 7;
        int ix = lox + kd, iy = loy + kh, iz = loz + kw;
        bool m = (ix < hix) && (iy < hiy) && (iz < hiz);
        if (ix >= hix) ix = lox;
        if (iy >= hiy) iy = loy;
        if (iz >= hiz) iz = loz;
        int flat = (ix * DP + iy) * DP + iz;
        s_flat[w] = m ? flat : (flat | (int)0x80000000);
    }
    __syncthreads();

    const float NEG_INF = -__builtin_inff();

    float sc0 = NEG_INF, sc1 = NEG_INF, sc2 = NEG_INF;
    {
        int fv = s_flat[p];
        if (fv >= 0) sc0 = Ksc[h * NPOS + fv];
        fv = s_flat[p + 128];
        if (fv >= 0) sc1 = Ksc[h * NPOS + fv];
        if (p + 256 < WIN3) {
            fv = s_flat[p + 256];
            if (fv >= 0) sc2 = Ksc[h * NPOS + fv];
        }
    }

    float lmax = fmaxf(fmaxf(sc0, sc1), sc2);
    #pragma unroll
    for (int off = 32; off; off >>= 1) lmax = fmaxf(lmax, __shfl_xor(lmax, off));
    if (lane == 0) s_red[wv] = lmax;
    __syncthreads();
    const float gmax = fmaxf(s_red[2 * h], s_red[2 * h + 1]);

    float e0 = (sc0 == NEG_INF) ? 0.0f : expf(sc0 - gmax);
    float e1 = (sc1 == NEG_INF) ? 0.0f : expf(sc1 - gmax);
    float e2 = 0.0f;
    s_attn[h][p]       = e0;
    s_attn[h][p + 128] = e1;
    if (p + 256 < WIN3) {
        e2 = (sc2 == NEG_INF) ? 0.0f : expf(sc2 - gmax);
        s_attn[h][p + 256] = e2;
    }
    float lsum = e0 + e1 + e2;
    #pragma unroll
    for (int off = 32; off; off >>= 1) lsum += __shfl_xor(lsum, off);
    if (lane == 0) s_red2[wv] = lsum;
    __syncthreads();
    if (tid < 2) s_gsum[tid] = s_red2[2 * tid] + s_red2[2 * tid + 1];
    __syncthreads();

    const int hh = lane >> 5;
    float acc = 0.0f;
    for (int w = wv; w < WIN3; w += 4) {
        int fv = s_flat[w] & 0x7fffffff;
        acc = fmaf(s_attn[hh][w], V[(size_t)fv * NCH + lane], acc);
    }

    s_pctx[wv][lane] = acc;
    __syncthreads();
    if (wv == 0) {
        float ctx = s_pctx[0][lane] + s_pctx[1][lane] + s_pctx[2][lane] + s_pctx[3][lane];
        s_ctx[lane] = ctx / s_gsum[hh];
    }
    __syncthreads();

    if (tid < 3) {
        float a = out_b[tid];
        #pragma unroll
        for (int j = 0; j < NCH; ++j) a = fmaf(out_w[tid * NCH + j], s_ctx[j], a);
        out[tid * NG + g] = a;
    }
}

// ---------------------------------------------------------------------------
extern "C" void kernel_launch(void* const* d_in, const int* in_sizes, int n_in,
                              void* d_out, int out_size, void* d_ws, size_t ws_size,
                              hipStream_t stream) {
    const float* feat  = (const float*)d_in[0];
    const float* dw_w  = (const float*)d_in[1];
    const float* dw_b  = (const float*)d_in[2];
    const float* pw_w  = (const float*)d_in[3];
    const float* pw_b  = (const float*)d_in[4];
    const float* k_w   = (const float*)d_in[5];
    const float* v_w   = (const float*)d_in[6];
    const float* out_w = (const float*)d_in[7];
    const float* out_b = (const float*)d_in[8];
    float* out = (float*)d_out;

    float* dwout = (float*)d_ws;                        // [64][NPOS]   28 MB
    float* f2T   = dwout + (size_t)NCH * NPOS;          // [32][NPOS]   14 MB
    float* V     = f2T + (size_t)NC2 * NPOS;            // [NPOS][64]   28 MB
    float* Ksc   = V + (size_t)NPOS * NCH;              // [2][NPOS]    .9 MB

    hipLaunchKernelGGL(dwconv8, dim3(54, NCH), dim3(256), 0, stream,
                       feat, dw_w, dw_b, dwout);
    hipLaunchKernelGGL(pw1, dim3(NPOS * 2 / 256), dim3(256), 0, stream,   // 864 blocks
                       dwout, pw_w, pw_b, f2T);
    hipLaunchKernelGGL(pw2, dim3(NPOS * 4 / 256), dim3(256), 0, stream,   // 1728 blocks
                       f2T, v_w, V);
    hipLaunchKernelGGL(ksc_k, dim3(NPOS / 256), dim3(256), 0, stream,     // 432 blocks
                       f2T, k_w, Ksc);
    // PROBE: 5x identical idempotent launches of attn_out.
    // A_attn = (T_this_round - 133.7) / 4.
    for (int rep = 0; rep < 5; ++rep) {
        hipLaunchKernelGGL(attn_out, dim3(NG), dim3(256), 0, stream,
                           V, Ksc, out_w, out_b, out);
    }
}

// Round 10
// 85.951 us; speedup vs baseline: 3.8231x; 3.1888x over previous
//
#include <hip/hip_runtime.h>
#include <stdint.h>

#define DIN 96
#define DP 48
#define NPOS (48*48*48)   // 110592
#define NG 1728           // 12^3
#define WIN3 343
#define NCH 64
#define NC2 32

// ---------------------------------------------------------------------------
// Kernel A: depthwise 3x3x3 stride-2 pad-1 conv + bias -> dwout[c][pos]
// (unchanged; ~49 us measured, HBM floor ~35)
// ---------------------------------------------------------------------------
__global__ __launch_bounds__(256) void dwconv8(
    const float* __restrict__ feat,   // [64][96][96][96]
    const float* __restrict__ dw_w,   // [64][27]
    const float* __restrict__ dw_b,   // [64]
    float* __restrict__ dwout)        // [64][NPOS]
{
    const int c   = blockIdx.y;
    const int idx = blockIdx.x * 256 + threadIdx.x;   // 0..13823
    const int t   = idx % 12;                         // w-quad (out w = 4t..4t+3)
    const int oh  = (idx / 12) % 48;
    const int odp = idx / (12 * 48);                  // d-pair (out d = 2odp,2odp+1)

    const float* fc = feat + (size_t)c * (DIN * DIN * DIN);
    const float* wc = dw_w + c * 27;
    float w[27];
    #pragma unroll
    for (int i = 0; i < 27; ++i) w[i] = wc[i];        // wave-uniform

    float acc[2][4];
    #pragma unroll
    for (int i = 0; i < 2; ++i)
        #pragma unroll
        for (int j = 0; j < 4; ++j) acc[i][j] = 0.0f;

    #pragma unroll
    for (int dd = 0; dd < 5; ++dd) {
        const int id = 4 * odp - 1 + dd;              // input plane
        if (id >= 0) {
            #pragma unroll
            for (int kh = 0; kh < 3; ++kh) {
                const int ih = 2 * oh - 1 + kh;       // input row
                if (ih >= 0) {
                    const float* row = fc + ((size_t)id * DIN + ih) * DIN + 8 * t;
                    const float4 a4 = *(const float4*)(row);
                    const float4 b4 = *(const float4*)(row + 4);
                    const float  s  = (t > 0) ? row[-1] : 0.0f;   // w = 8t-1 (pad 0)
                    #pragma unroll
                    for (int half = 0; half < 2; ++half) {
                        if ((half == 0 && dd <= 2) || (half == 1 && dd >= 2)) {
                            const int kd = (half == 0) ? dd : dd - 2;
                            const float w0 = w[(kd * 3 + kh) * 3 + 0];
                            const float w1 = w[(kd * 3 + kh) * 3 + 1];
                            const float w2 = w[(kd * 3 + kh) * 3 + 2];
                            acc[half][0] = fmaf(s,    w0, fmaf(a4.x, w1, fmaf(a4.y, w2, acc[half][0])));
                            acc[half][1] = fmaf(a4.y, w0, fmaf(a4.z, w1, fmaf(a4.w, w2, acc[half][1])));
                            acc[half][2] = fmaf(a4.w, w0, fmaf(b4.x, w1, fmaf(b4.y, w2, acc[half][2])));
                            acc[half][3] = fmaf(b4.y, w0, fmaf(b4.z, w1, fmaf(b4.w, w2, acc[half][3])));
                        }
                    }
                }
            }
        }
    }

    const float b = dw_b[c];
    const size_t base = (size_t)c * NPOS + (((size_t)(2 * odp) * DP + oh) * DP) + 4 * t;
    *(float4*)(dwout + base)           = make_float4(acc[0][0] + b, acc[0][1] + b, acc[0][2] + b, acc[0][3] + b);
    *(float4*)(dwout + base + DP * DP) = make_float4(acc[1][0] + b, acc[1][1] + b, acc[1][2] + b, acc[1][3] + b);
}

// ---------------------------------------------------------------------------
// Kernel B1: pointwise (64->32)+bias+ReLU -> f2T[32][NPOS] (transposed)
// (unchanged)
// ---------------------------------------------------------------------------
__global__ __launch_bounds__(256) void pw1(
    const float* __restrict__ dwout,  // [64][NPOS]
    const float* __restrict__ pw_w,   // [32][64]
    const float* __restrict__ pw_b,   // [32]
    float* __restrict__ f2T)          // [32][NPOS]
{
    __shared__ float swT[NCH * NC2];  // swT[c*32+o] = pw_w[o*64+c]
    __shared__ float sb[NC2];
    const int tid = threadIdx.x;

    for (int i = tid; i < NCH * NC2; i += 256) {
        const int o = i & 31, c = i >> 5;
        swT[i] = pw_w[o * NCH + c];
    }
    if (tid < NC2) sb[tid] = pw_b[tid];
    __syncthreads();

    const int g  = blockIdx.x * 256 + tid;
    const int oq = g & 7;             // out-ch group: 4*oq .. 4*oq+3
    const int p4 = g >> 3;            // positions 4*p4 .. 4*p4+3

    float acc[4][4];                  // [ch][pos]
    #pragma unroll
    for (int i = 0; i < 4; ++i) {
        const float b = sb[oq * 4 + i];
        #pragma unroll
        for (int j = 0; j < 4; ++j) acc[i][j] = b;
    }

    const float* xp = dwout + 4 * (size_t)p4;
    #pragma unroll 4
    for (int c = 0; c < NCH; ++c) {
        const float4 x4 = *(const float4*)(xp + (size_t)c * NPOS);
        const float4 w4 = *(const float4*)(swT + c * NC2 + oq * 4);
        const float xs[4] = {x4.x, x4.y, x4.z, x4.w};
        const float ws[4] = {w4.x, w4.y, w4.z, w4.w};
        #pragma unroll
        for (int i = 0; i < 4; ++i)
            #pragma unroll
            for (int j = 0; j < 4; ++j)
                acc[i][j] = fmaf(ws[i], xs[j], acc[i][j]);
    }

    #pragma unroll
    for (int i = 0; i < 4; ++i) {
        const int o = oq * 4 + i;
        *(float4*)(f2T + (size_t)o * NPOS + 4 * p4) =
            make_float4(fmaxf(acc[i][0], 0.f), fmaxf(acc[i][1], 0.f),
                        fmaxf(acc[i][2], 0.f), fmaxf(acc[i][3], 0.f));
    }
}

// ---------------------------------------------------------------------------
// Kernel B2 (NEW): fused K-score + out_w-projected V  -> VP8[NPOS][8]
//   row = { k0, k1, vp[h0][o0..2], vp[h1][o0..2] }
//   WC[0..1][k] = k_w[h*32][k] / sqrt(32)
//   WC[2+h*3+o][k] = sum_c out_w[o][h*32+c] * v_w[h*32+c][k]
// ---------------------------------------------------------------------------
__global__ __launch_bounds__(256) void kvp8(
    const float* __restrict__ f2T,    // [32][NPOS]
    const float* __restrict__ k_w,    // [64][32]
    const float* __restrict__ v_w,    // [64][32]
    const float* __restrict__ out_w,  // [3][64]
    float* __restrict__ VP8)          // [NPOS][8]
{
    __shared__ float WC[8][NC2];
    const int tid = threadIdx.x;

    if (tid < 64) {                   // k rows, prescaled
        const int h = tid >> 5, o = tid & 31;
        WC[h][o] = k_w[(h * 32) * NC2 + o] * 0.17677669529663687f;
    }
    if (tid < 192) {                  // W2 rows
        const int row = tid >> 5, k = tid & 31;   // row 0..5
        const int h = row / 3, oo = row % 3;
        float a = 0.f;
        #pragma unroll
        for (int c = 0; c < NC2; ++c)
            a = fmaf(out_w[oo * NCH + h * 32 + c], v_w[(h * 32 + c) * NC2 + k], a);
        WC[2 + row][k] = a;
    }
    __syncthreads();

    const int pos = blockIdx.x * 256 + tid;
    float acc[8];
    #pragma unroll
    for (int r = 0; r < 8; ++r) acc[r] = 0.f;

    #pragma unroll 8
    for (int o = 0; o < NC2; ++o) {
        const float x = f2T[(size_t)o * NPOS + pos];
        #pragma unroll
        for (int r = 0; r < 8; ++r)
            acc[r] = fmaf(WC[r][o], x, acc[r]);   // LDS broadcast reads
    }

    float4* vp = (float4*)(VP8 + (size_t)pos * 8);
    vp[0] = make_float4(acc[0], acc[1], acc[2], acc[3]);
    vp[1] = make_float4(acc[4], acc[5], acc[6], acc[7]);
}

// ---------------------------------------------------------------------------
// Kernel C (NEW): windowed attention entirely from VP8.
// Per block: 343 slots, thread owns slot tid (+ tid+256). One 32B row per
// slot holds both heads' scores AND the 6 projected values -> all register-
// resident; softmax + 8-value block reduction; 3 output floats.
// ---------------------------------------------------------------------------
__global__ __launch_bounds__(256) void attn_vp(
    const float* __restrict__ VP8,    // [NPOS][8]
    const float* __restrict__ out_b,  // [3]
    float* __restrict__ out)          // [3][NG]
{
    const int lo_t[12] = {0,1,5,9,14,18,22,26,31,35,39,44};
    const int hi_t[12] = {4,8,12,16,21,25,29,33,38,42,46,48};

    const int g    = blockIdx.x;
    const int tid  = threadIdx.x;
    const int lane = tid & 63;
    const int wv   = tid >> 6;

    const int gz = g % 12, gy = (g / 12) % 12, gx = g / 144;
    const int lox = lo_t[gx], hix = hi_t[gx];
    const int loy = lo_t[gy], hiy = hi_t[gy];
    const int loz = lo_t[gz], hiz = hi_t[gz];

    const float NEG_INF = -__builtin_inff();

    float4 lo0, hi0, lo1, hi1;
    {   // slot 0 = tid (always < 343)
        const int s = tid;
        const int kd = s / 49, kh = (s / 7) % 7, kw = s % 7;
        const int ix = lox + kd, iy = loy + kh, iz = loz + kw;
        if (ix < hix && iy < hiy && iz < hiz) {
            const int fv = (ix * DP + iy) * DP + iz;
            const float4* p = (const float4*)(VP8 + (size_t)fv * 8);
            lo0 = p[0]; hi0 = p[1];
        } else {
            lo0 = make_float4(NEG_INF, NEG_INF, 0.f, 0.f);
            hi0 = make_float4(0.f, 0.f, 0.f, 0.f);
        }
    }
    {   // slot 1 = tid + 256
        const int s = tid + 256;
        lo1 = make_float4(NEG_INF, NEG_INF, 0.f, 0.f);
        hi1 = make_float4(0.f, 0.f, 0.f, 0.f);
        if (s < WIN3) {
            const int kd = s / 49, kh = (s / 7) % 7, kw = s % 7;
            const int ix = lox + kd, iy = loy + kh, iz = loz + kw;
            if (ix < hix && iy < hiy && iz < hiz) {
                const int fv = (ix * DP + iy) * DP + iz;
                const float4* p = (const float4*)(VP8 + (size_t)fv * 8);
                lo1 = p[0]; hi1 = p[1];
            }
        }
    }

    __shared__ float sred[4][8];

    // block max per head
    float m0 = fmaxf(lo0.x, lo1.x);
    float m1 = fmaxf(lo0.y, lo1.y);
    #pragma unroll
    for (int off = 32; off; off >>= 1) {
        m0 = fmaxf(m0, __shfl_xor(m0, off));
        m1 = fmaxf(m1, __shfl_xor(m1, off));
    }
    if (lane == 0) { sred[wv][0] = m0; sred[wv][1] = m1; }
    __syncthreads();
    const float g0 = fmaxf(fmaxf(sred[0][0], sred[1][0]), fmaxf(sred[2][0], sred[3][0]));
    const float g1 = fmaxf(fmaxf(sred[0][1], sred[1][1]), fmaxf(sred[2][1], sred[3][1]));
    __syncthreads();   // protect sred before reuse

    // exp (masked slots have score=-inf -> e=0 exactly)
    const float e00 = expf(lo0.x - g0), e01 = expf(lo0.y - g1);
    const float e10 = expf(lo1.x - g0), e11 = expf(lo1.y - g1);

    float acc[8];
    acc[0] = e00 + e10;                            // sum head0
    acc[1] = e01 + e11;                            // sum head1
    acc[2] = e00 * lo0.z + e10 * lo1.z;            // h0 o0
    acc[3] = e00 * lo0.w + e10 * lo1.w;            // h0 o1
    acc[4] = e00 * hi0.x + e10 * hi1.x;            // h0 o2
    acc[5] = e01 * hi0.y + e11 * hi1.y;            // h1 o0
    acc[6] = e01 * hi0.z + e11 * hi1.z;            // h1 o1
    acc[7] = e01 * hi0.w + e11 * hi1.w;            // h1 o2

    #pragma unroll
    for (int j = 0; j < 8; ++j) {
        #pragma unroll
        for (int off = 32; off; off >>= 1) acc[j] += __shfl_xor(acc[j], off);
    }
    if (lane == 0) {
        #pragma unroll
        for (int j = 0; j < 8; ++j) sred[wv][j] = acc[j];
    }
    __syncthreads();

    if (tid < 3) {
        const float s0 = sred[0][0] + sred[1][0] + sred[2][0] + sred[3][0];
        const float s1 = sred[0][1] + sred[1][1] + sred[2][1] + sred[3][1];
        const float a0 = sred[0][2 + tid] + sred[1][2 + tid] + sred[2][2 + tid] + sred[3][2 + tid];
        const float a1 = sred[0][5 + tid] + sred[1][5 + tid] + sred[2][5 + tid] + sred[3][5 + tid];
        out[tid * NG + g] = out_b[tid] + a0 / s0 + a1 / s1;
    }
}

// ---------------------------------------------------------------------------
extern "C" void kernel_launch(void* const* d_in, const int* in_sizes, int n_in,
                              void* d_out, int out_size, void* d_ws, size_t ws_size,
                              hipStream_t stream) {
    const float* feat  = (const float*)d_in[0];
    const float* dw_w  = (const float*)d_in[1];
    const float* dw_b  = (const float*)d_in[2];
    const float* pw_w  = (const float*)d_in[3];
    const float* pw_b  = (const float*)d_in[4];
    const float* k_w   = (const float*)d_in[5];
    const float* v_w   = (const float*)d_in[6];
    const float* out_w = (const float*)d_in[7];
    const float* out_b = (const float*)d_in[8];
    float* out = (float*)d_out;

    float* dwout = (float*)d_ws;                        // [64][NPOS]   28 MB
    float* f2T   = dwout + (size_t)NCH * NPOS;          // [32][NPOS]   14 MB
    float* VP8   = f2T + (size_t)NC2 * NPOS;            // [NPOS][8]   3.5 MB

    hipLaunchKernelGGL(dwconv8, dim3(54, NCH), dim3(256), 0, stream,
                       feat, dw_w, dw_b, dwout);
    hipLaunchKernelGGL(pw1, dim3(NPOS * 2 / 256), dim3(256), 0, stream,   // 864 blocks
                       dwout, pw_w, pw_b, f2T);
    hipLaunchKernelGGL(kvp8, dim3(NPOS / 256), dim3(256), 0, stream,      // 432 blocks
                       f2T, k_w, v_w, out_w, VP8);
    hipLaunchKernelGGL(attn_vp, dim3(NG), dim3(256), 0, stream,
                       VP8, out_b, out);
}

// Round 11
// 84.135 us; speedup vs baseline: 3.9057x; 1.0216x over previous
//
#include <hip/hip_runtime.h>
#include <stdint.h>

#define DIN 96
#define DP 48
#define NPOS (48*48*48)   // 110592
#define NG 1728           // 12^3
#define WIN3 343
#define NCH 64
#define NC2 32

// ---------------------------------------------------------------------------
// Kernel A: depthwise 3x3x3 stride-2 pad-1 conv + bias -> dwout[c][pos]
// 2(d) x 2(h) x 4(w) = 16 outputs/thread. 25 rows x 3 loads = 75 loads,
// 16 independent chains. Grid (27, 64).
// ---------------------------------------------------------------------------
__global__ __launch_bounds__(256) void dwconv16(
    const float* __restrict__ feat,   // [64][96][96][96]
    const float* __restrict__ dw_w,   // [64][27]
    const float* __restrict__ dw_b,   // [64]
    float* __restrict__ dwout)        // [64][NPOS]
{
    const int c   = blockIdx.y;
    const int idx = blockIdx.x * 256 + threadIdx.x;   // 0..6911
    const int t   = idx % 12;                         // w-quad (ow = 4t..4t+3)
    const int ohp = (idx / 12) % 24;                  // h-pair (oh = 2ohp,2ohp+1)
    const int odp = idx / (12 * 24);                  // d-pair (od = 2odp,2odp+1)

    const float* fc = feat + (size_t)c * (DIN * DIN * DIN);
    const float* wc = dw_w + c * 27;
    float w[27];
    #pragma unroll
    for (int i = 0; i < 27; ++i) w[i] = wc[i];        // wave-uniform

    float acc[2][2][4];
    #pragma unroll
    for (int a = 0; a < 2; ++a)
        #pragma unroll
        for (int b = 0; b < 2; ++b)
            #pragma unroll
            for (int j = 0; j < 4; ++j) acc[a][b][j] = 0.0f;

    #pragma unroll
    for (int dd = 0; dd < 5; ++dd) {
        const int id = 4 * odp - 1 + dd;              // input plane
        if (id >= 0) {
            #pragma unroll
            for (int hh = 0; hh < 5; ++hh) {
                const int ih = 4 * ohp - 1 + hh;      // input row
                if (ih >= 0) {
                    const float* row = fc + ((size_t)id * DIN + ih) * DIN + 8 * t;
                    const float4 a4 = *(const float4*)(row);
                    const float4 b4 = *(const float4*)(row + 4);
                    const float  s  = (t > 0) ? row[-1] : 0.0f;   // w = 8t-1 (pad 0)
                    #pragma unroll
                    for (int dh = 0; dh < 2; ++dh) {
                        if ((dh == 0 && dd <= 2) || (dh == 1 && dd >= 2)) {
                            const int kd = dd - 2 * dh;
                            #pragma unroll
                            for (int hf = 0; hf < 2; ++hf) {
                                if ((hf == 0 && hh <= 2) || (hf == 1 && hh >= 2)) {
                                    const int kh = hh - 2 * hf;
                                    const float w0 = w[(kd * 3 + kh) * 3 + 0];
                                    const float w1 = w[(kd * 3 + kh) * 3 + 1];
                                    const float w2 = w[(kd * 3 + kh) * 3 + 2];
                                    float* ac = acc[dh][hf];
                                    ac[0] = fmaf(s,    w0, fmaf(a4.x, w1, fmaf(a4.y, w2, ac[0])));
                                    ac[1] = fmaf(a4.y, w0, fmaf(a4.z, w1, fmaf(a4.w, w2, ac[1])));
                                    ac[2] = fmaf(a4.w, w0, fmaf(b4.x, w1, fmaf(b4.y, w2, ac[2])));
                                    ac[3] = fmaf(b4.y, w0, fmaf(b4.z, w1, fmaf(b4.w, w2, ac[3])));
                                }
                            }
                        }
                    }
                }
            }
        }
    }

    const float b = dw_b[c];
    const size_t base = (size_t)c * NPOS + (((size_t)(2 * odp) * DP + 2 * ohp) * DP) + 4 * t;
    #pragma unroll
    for (int dh = 0; dh < 2; ++dh)
        #pragma unroll
        for (int hf = 0; hf < 2; ++hf) {
            const float* ac = acc[dh][hf];
            *(float4*)(dwout + base + (size_t)dh * DP * DP + (size_t)hf * DP) =
                make_float4(ac[0] + b, ac[1] + b, ac[2] + b, ac[3] + b);
        }
}

// ---------------------------------------------------------------------------
// Kernel B (FUSED pw1+kvp8): pointwise(64->32)+ReLU then K/V-proj -> VP8.
// Block = 128 positions. Phase 1: pw1 shape (4ch x 4pos / thread, weights in
// LDS). Exchange f2 via LDS [128][33]. Phase 2: 2 threads/pos, 4 VP8 each.
//   VP8 row = { k0, k1, vp[h0][o0..2], vp[h1][o0..2] }
// ---------------------------------------------------------------------------
__global__ __launch_bounds__(256) void pwk(
    const float* __restrict__ dwout,  // [64][NPOS]
    const float* __restrict__ pw_w,   // [32][64]
    const float* __restrict__ pw_b,   // [32]
    const float* __restrict__ k_w,    // [64][32]
    const float* __restrict__ v_w,    // [64][32]
    const float* __restrict__ out_w,  // [3][64]
    float* __restrict__ VP8)          // [NPOS][8]
{
    __shared__ float swT[NCH * NC2];  // swT[c*32+o] = pw_w[o*64+c]
    __shared__ float sb[NC2];
    __shared__ float WC[8][NC2];
    __shared__ float f2s[128][33];
    const int tid = threadIdx.x;

    for (int i = tid; i < NCH * NC2; i += 256) {
        const int o = i & 31, c = i >> 5;
        swT[i] = pw_w[o * NCH + c];
    }
    if (tid < NC2) sb[tid] = pw_b[tid];
    if (tid < 64) {                   // K rows, prescaled
        const int h = tid >> 5, o = tid & 31;
        WC[h][o] = k_w[(h * 32) * NC2 + o] * 0.17677669529663687f;
    } else if (tid < 256 && tid >= 64 && tid < 64 + 192) {  // W2 rows
        const int r = (tid - 64) >> 5, k = (tid - 64) & 31;  // r 0..5
        const int h = r / 3, oo = r % 3;
        float a = 0.f;
        #pragma unroll
        for (int c = 0; c < NC2; ++c)
            a = fmaf(out_w[oo * NCH + h * 32 + c], v_w[(h * 32 + c) * NC2 + k], a);
        WC[2 + r][k] = a;
    }
    __syncthreads();

    // ---- phase 1: pointwise, 4 out-ch x 4 positions per thread ----
    const int oq = tid & 7;           // out-ch group: 4*oq .. 4*oq+3
    const int p4 = tid >> 3;          // local position quad 0..31
    const size_t pos0 = (size_t)blockIdx.x * 128;

    float acc[4][4];                  // [ch][pos]
    #pragma unroll
    for (int i = 0; i < 4; ++i) {
        const float b = sb[oq * 4 + i];
        #pragma unroll
        for (int j = 0; j < 4; ++j) acc[i][j] = b;
    }

    const float* xp = dwout + pos0 + 4 * (size_t)p4;
    #pragma unroll 4
    for (int c = 0; c < NCH; ++c) {
        const float4 x4 = *(const float4*)(xp + (size_t)c * NPOS);
        const float4 w4 = *(const float4*)(swT + c * NC2 + oq * 4);
        const float xs[4] = {x4.x, x4.y, x4.z, x4.w};
        const float ws[4] = {w4.x, w4.y, w4.z, w4.w};
        #pragma unroll
        for (int i = 0; i < 4; ++i)
            #pragma unroll
            for (int j = 0; j < 4; ++j)
                acc[i][j] = fmaf(ws[i], xs[j], acc[i][j]);
    }

    #pragma unroll
    for (int j = 0; j < 4; ++j) {
        const int pl = p4 * 4 + j;
        #pragma unroll
        for (int i = 0; i < 4; ++i)
            f2s[pl][oq * 4 + i] = fmaxf(acc[i][j], 0.f);
    }
    __syncthreads();

    // ---- phase 2: 2 threads per position, 4 VP8 outputs each ----
    const int q  = tid & 1;           // output group q*4..q*4+3
    const int pl = tid >> 1;          // local position 0..127
    float a8[4] = {0.f, 0.f, 0.f, 0.f};
    #pragma unroll 8
    for (int o = 0; o < NC2; ++o) {
        const float x = f2s[pl][o];
        #pragma unroll
        for (int r = 0; r < 4; ++r)
            a8[r] = fmaf(WC[q * 4 + r][o], x, a8[r]);
    }
    *(float4*)(VP8 + (pos0 + pl) * 8 + q * 4) = make_float4(a8[0], a8[1], a8[2], a8[3]);
}

// ---------------------------------------------------------------------------
// Kernel C: windowed attention from VP8 (unchanged).
// ---------------------------------------------------------------------------
__global__ __launch_bounds__(256) void attn_vp(
    const float* __restrict__ VP8,    // [NPOS][8]
    const float* __restrict__ out_b,  // [3]
    float* __restrict__ out)          // [3][NG]
{
    const int lo_t[12] = {0,1,5,9,14,18,22,26,31,35,39,44};
    const int hi_t[12] = {4,8,12,16,21,25,29,33,38,42,46,48};

    const int g    = blockIdx.x;
    const int tid  = threadIdx.x;
    const int lane = tid & 63;
    const int wv   = tid >> 6;

    const int gz = g % 12, gy = (g / 12) % 12, gx = g / 144;
    const int lox = lo_t[gx], hix = hi_t[gx];
    const int loy = lo_t[gy], hiy = hi_t[gy];
    const int loz = lo_t[gz], hiz = hi_t[gz];

    const float NEG_INF = -__builtin_inff();

    float4 lo0, hi0, lo1, hi1;
    {   // slot 0 = tid (always < 343)
        const int s = tid;
        const int kd = s / 49, kh = (s / 7) % 7, kw = s % 7;
        const int ix = lox + kd, iy = loy + kh, iz = loz + kw;
        if (ix < hix && iy < hiy && iz < hiz) {
            const int fv = (ix * DP + iy) * DP + iz;
            const float4* p = (const float4*)(VP8 + (size_t)fv * 8);
            lo0 = p[0]; hi0 = p[1];
        } else {
            lo0 = make_float4(NEG_INF, NEG_INF, 0.f, 0.f);
            hi0 = make_float4(0.f, 0.f, 0.f, 0.f);
        }
    }
    {   // slot 1 = tid + 256
        const int s = tid + 256;
        lo1 = make_float4(NEG_INF, NEG_INF, 0.f, 0.f);
        hi1 = make_float4(0.f, 0.f, 0.f, 0.f);
        if (s < WIN3) {
            const int kd = s / 49, kh = (s / 7) % 7, kw = s % 7;
            const int ix = lox + kd, iy = loy + kh, iz = loz + kw;
            if (ix < hix && iy < hiy && iz < hiz) {
                const int fv = (ix * DP + iy) * DP + iz;
                const float4* p = (const float4*)(VP8 + (size_t)fv * 8);
                lo1 = p[0]; hi1 = p[1];
            }
        }
    }

    __shared__ float sred[4][8];

    float m0 = fmaxf(lo0.x, lo1.x);
    float m1 = fmaxf(lo0.y, lo1.y);
    #pragma unroll
    for (int off = 32; off; off >>= 1) {
        m0 = fmaxf(m0, __shfl_xor(m0, off));
        m1 = fmaxf(m1, __shfl_xor(m1, off));
    }
    if (lane == 0) { sred[wv][0] = m0; sred[wv][1] = m1; }
    __syncthreads();
    const float g0 = fmaxf(fmaxf(sred[0][0], sred[1][0]), fmaxf(sred[2][0], sred[3][0]));
    const float g1 = fmaxf(fmaxf(sred[0][1], sred[1][1]), fmaxf(sred[2][1], sred[3][1]));
    __syncthreads();

    const float e00 = expf(lo0.x - g0), e01 = expf(lo0.y - g1);
    const float e10 = expf(lo1.x - g0), e11 = expf(lo1.y - g1);

    float acc[8];
    acc[0] = e00 + e10;
    acc[1] = e01 + e11;
    acc[2] = e00 * lo0.z + e10 * lo1.z;
    acc[3] = e00 * lo0.w + e10 * lo1.w;
    acc[4] = e00 * hi0.x + e10 * hi1.x;
    acc[5] = e01 * hi0.y + e11 * hi1.y;
    acc[6] = e01 * hi0.z + e11 * hi1.z;
    acc[7] = e01 * hi0.w + e11 * hi1.w;

    #pragma unroll
    for (int j = 0; j < 8; ++j) {
        #pragma unroll
        for (int off = 32; off; off >>= 1) acc[j] += __shfl_xor(acc[j], off);
    }
    if (lane == 0) {
        #pragma unroll
        for (int j = 0; j < 8; ++j) sred[wv][j] = acc[j];
    }
    __syncthreads();

    if (tid < 3) {
        const float s0 = sred[0][0] + sred[1][0] + sred[2][0] + sred[3][0];
        const float s1 = sred[0][1] + sred[1][1] + sred[2][1] + sred[3][1];
        const float a0 = sred[0][2 + tid] + sred[1][2 + tid] + sred[2][2 + tid] + sred[3][2 + tid];
        const float a1 = sred[0][5 + tid] + sred[1][5 + tid] + sred[2][5 + tid] + sred[3][5 + tid];
        out[tid * NG + g] = out_b[tid] + a0 / s0 + a1 / s1;
    }
}

// ---------------------------------------------------------------------------
extern "C" void kernel_launch(void* const* d_in, const int* in_sizes, int n_in,
                              void* d_out, int out_size, void* d_ws, size_t ws_size,
                              hipStream_t stream) {
    const float* feat  = (const float*)d_in[0];
    const float* dw_w  = (const float*)d_in[1];
    const float* dw_b  = (const float*)d_in[2];
    const float* pw_w  = (const float*)d_in[3];
    const float* pw_b  = (const float*)d_in[4];
    const float* k_w   = (const float*)d_in[5];
    const float* v_w   = (const float*)d_in[6];
    const float* out_w = (const float*)d_in[7];
    const float* out_b = (const float*)d_in[8];
    float* out = (float*)d_out;

    float* dwout = (float*)d_ws;                        // [64][NPOS]   28 MB
    float* VP8   = dwout + (size_t)NCH * NPOS;          // [NPOS][8]   3.5 MB

    hipLaunchKernelGGL(dwconv16, dim3(27, NCH), dim3(256), 0, stream,
                       feat, dw_w, dw_b, dwout);
    hipLaunchKernelGGL(pwk, dim3(NPOS / 128), dim3(256), 0, stream,       // 864 blocks
                       dwout, pw_w, pw_b, k_w, v_w, out_w, VP8);
    hipLaunchKernelGGL(attn_vp, dim3(NG), dim3(256), 0, stream,
                       VP8, out_b, out);
}